// Round 2
// baseline (51665.674 us; speedup 1.0000x reference)
//
#include <hip/hip_runtime.h>

typedef unsigned short u16;
typedef __attribute__((ext_vector_type(8))) short bf16x8;
typedef __attribute__((ext_vector_type(4))) float f32x4;

#define B_ 512
#define T_ 1024
#define F_ 128
#define H_ 512
#define G_ 2048
#define LH_ 1024

#define MFMA16(a,b,c) (c) = __builtin_amdgcn_mfma_f32_16x16x32_bf16((a),(b),(c),0,0,0)

__device__ __forceinline__ u16 f2bf(float f) {
  unsigned u = __float_as_uint(f);
  unsigned r = (u + 0x7fffu + ((u >> 16) & 1u)) >> 16;
  return (u16)r;
}
__device__ __forceinline__ float bf2f(u16 h) {
  return __uint_as_float(((unsigned)h) << 16);
}

// ---------------- workspace layout (bytes) ----------------
constexpr size_t SZ_HBUF   = (size_t)2 * B_ * H_ * 2;       // 1,048,576 (double buffered)
constexpr size_t O_HHI     = 0;
constexpr size_t O_HLO     = O_HHI + SZ_HBUF;
constexpr size_t O_BAR     = O_HLO + SZ_HBUF;               // 2,097,152
constexpr size_t O_MSET    = O_BAR + 4096;                  // memset [0, O_MSET)
constexpr size_t O_WHH_HI  = O_MSET;
constexpr size_t O_WHH_LO  = O_WHH_HI + (size_t)G_ * H_ * 2;
constexpr size_t O_WIH_HI  = O_WHH_LO + (size_t)G_ * H_ * 2;
constexpr size_t O_WIH_LO  = O_WIH_HI + (size_t)G_ * F_ * 2;
constexpr size_t O_BIAS    = O_WIH_LO + (size_t)G_ * F_ * 2;
constexpr size_t O_HT      = O_BIAS + (size_t)G_ * 4;
constexpr size_t O_Z       = O_HT + (size_t)B_ * H_ * 4;
constexpr size_t WS_NEED   = O_Z + (size_t)B_ * LH_ * 4;    // ~10.5 MB

// LDS carve (dynamic): 151,808 B total
constexpr unsigned SM_WIH_HI = 0;        // [64][128] u16 swizzled
constexpr unsigned SM_WIH_LO = 16384;
constexpr unsigned SM_X_HI   = 32768;    // [64][128] u16 swizzled
constexpr unsigned SM_X_LO   = 49152;
constexpr unsigned SM_CHUNK  = 65536;    // [2 dbuf][4 bufs][64][64] u16 = 64 KB
constexpr unsigned SM_GATES  = 131072;   // [64][64] f32
constexpr unsigned SM_C      = 147456;   // [64][16] f32
constexpr unsigned SM_BIAS   = 151552;   // [64] f32
constexpr unsigned SMEM_BYTES = 151808;

// ---------------- weight prep: permute + split to hi/lo bf16 ----------------
// permuted gate-col P = 64*nb + 16*g + u'  (unit u = 16*nb + u', gate g in {i,f,g,o})
__global__ void prep_weights(const float* __restrict__ Wih, const float* __restrict__ Whh,
                             const float* __restrict__ bih, const float* __restrict__ bhh,
                             u16* __restrict__ WhhHi, u16* __restrict__ WhhLo,
                             u16* __restrict__ WihHi, u16* __restrict__ WihLo,
                             float* __restrict__ bias) {
  int P = blockIdx.x;
  int nb = P >> 6, g = (P >> 4) & 3, u = P & 15;
  int orig = g * H_ + (nb << 4) + u;
  for (int k = threadIdx.x; k < H_; k += 128) {
    float w = Whh[(size_t)orig * H_ + k];
    u16 hi = f2bf(w);
    WhhHi[(size_t)P * H_ + k] = hi;
    WhhLo[(size_t)P * H_ + k] = f2bf(w - bf2f(hi));
  }
  if (threadIdx.x < 128) {
    int k = threadIdx.x;
    float w = Wih[(size_t)orig * F_ + k];
    u16 hi = f2bf(w);
    WihHi[(size_t)P * F_ + k] = hi;
    WihLo[(size_t)P * F_ + k] = f2bf(w - bf2f(hi));
  }
  if (threadIdx.x == 0) bias[P] = bih[orig] + bhh[orig];
}

// ---------------- helpers ----------------
__device__ __forceinline__ void gl2lds16(const void* g, void* lds) {
  __builtin_amdgcn_global_load_lds(
      (const __attribute__((address_space(1))) unsigned int*)g,
      (__attribute__((address_space(3))) unsigned int*)lds, 16, 0, 0);
}

// swizzled LDS fragment read: 8 contiguous bf16 at (row, k8*8), slot XORed with row
__device__ __forceinline__ bf16x8 ldf(const u16* base, int row, int k8, int stride, int mask) {
  return *(const bf16x8*)(base + row * stride + ((k8 ^ (row & mask)) << 3));
}

// stage one K=64 chunk (A=h hi/lo, B=Whh hi/lo) via async global->LDS, swizzled source
__device__ __forceinline__ void stage_chunk(char* sChunk, int db, int kc,
                                            const u16* hcH, const u16* hcL,
                                            const u16* WhhHi, const u16* WhhLo,
                                            int m, int nb, int w, int l) {
  const u16* srcbase;
  int row0;
  if (w == 0)      { srcbase = hcH;   row0 = 64 * m;  }
  else if (w == 1) { srcbase = hcL;   row0 = 64 * m;  }
  else if (w == 2) { srcbase = WhhHi; row0 = 64 * nb; }
  else             { srcbase = WhhLo; row0 = 64 * nb; }
  char* dst = sChunk + (db * 4 + w) * 8192;
  int k8 = (l & 7) ^ (l >> 3);             // pre-swizzled source k-group
  int coloff = kc * 64 + k8 * 8;
  #pragma unroll
  for (int j = 0; j < 8; ++j) {
    int row = 8 * j + (l >> 3);
    gl2lds16(srcbase + (size_t)(row0 + row) * H_ + coloff, dst + j * 1024);
  }
}

// ---------------- persistent LSTM kernel ----------------
__global__ __launch_bounds__(256, 1) void lstm_persistent(
    const float* __restrict__ x,
    const u16* __restrict__ WhhHi, const u16* __restrict__ WhhLo,
    const u16* __restrict__ WihHi, const u16* __restrict__ WihLo,
    const float* __restrict__ bias,
    u16* __restrict__ hHi, u16* __restrict__ hLo,
    unsigned* __restrict__ bar, float* __restrict__ hT) {
  extern __shared__ char smem[];
  u16* sWihHi   = (u16*)(smem + SM_WIH_HI);
  u16* sWihLo   = (u16*)(smem + SM_WIH_LO);
  u16* sXHi     = (u16*)(smem + SM_X_HI);
  u16* sXLo     = (u16*)(smem + SM_X_LO);
  char* sChunk  = smem + SM_CHUNK;
  float* sGates = (float*)(smem + SM_GATES);
  float* sC     = (float*)(smem + SM_C);
  float* sBias  = (float*)(smem + SM_BIAS);

  const int tid = threadIdx.x;
  const int w = tid >> 6, l = tid & 63;
  const int m  = blockIdx.x >> 5;   // row group 0..7 (64 batch rows)
  const int nb = blockIdx.x & 31;   // unit block 0..31 (16 units / 64 gate cols)
  const int mh = w & 1, nh = w >> 1;

  // ---- one-time init: Wih slice (swizzled), bias slice, c=0 ----
  {
    int c = tid >> 2;
    #pragma unroll
    for (int j = 0; j < 4; ++j) {
      int k8 = (tid & 3) * 4 + j;
      int s = k8 ^ (c & 15);
      *(bf16x8*)(sWihHi + c * 128 + s * 8) =
          *(const bf16x8*)(WihHi + (size_t)(64 * nb + c) * F_ + k8 * 8);
      *(bf16x8*)(sWihLo + c * 128 + s * 8) =
          *(const bf16x8*)(WihLo + (size_t)(64 * nb + c) * F_ + k8 * 8);
    }
    if (tid < 64) sBias[tid] = bias[64 * nb + tid];
    for (int i = tid; i < 1024; i += 256) sC[i] = 0.f;
  }
  __syncthreads();

  for (int t = 0; t < T_; ++t) {
    const int cur = t & 1;
    const u16* hcH = hHi + (size_t)cur * B_ * H_;
    const u16* hcL = hLo + (size_t)cur * B_ * H_;
    u16* hnH = hHi + (size_t)(cur ^ 1) * B_ * H_;
    u16* hnL = hLo + (size_t)(cur ^ 1) * B_ * H_;

    // ---- stage x tile (fp32 -> split bf16, swizzled) ----
    {
      int r = tid >> 2;
      const float* xs = x + (size_t)(64 * m + r) * T_ * F_ + (size_t)t * F_ + (tid & 3) * 32;
      #pragma unroll
      for (int j = 0; j < 4; ++j) {
        float4 v0 = *(const float4*)(xs + j * 8);
        float4 v1 = *(const float4*)(xs + j * 8 + 4);
        float fv[8] = {v0.x, v0.y, v0.z, v0.w, v1.x, v1.y, v1.z, v1.w};
        bf16x8 hi, lo;
        #pragma unroll
        for (int e = 0; e < 8; ++e) {
          u16 hb = f2bf(fv[e]);
          hi[e] = (short)hb;
          lo[e] = (short)f2bf(fv[e] - bf2f(hb));
        }
        int k8 = (tid & 3) * 4 + j;
        int s = k8 ^ (r & 15);
        *(bf16x8*)(sXHi + r * 128 + s * 8) = hi;
        *(bf16x8*)(sXLo + r * 128 + s * 8) = lo;
      }
    }
    __syncthreads();

    // prologue: async stage chunk 0 into dbuf 0 (overlaps with x-part MFMA)
    stage_chunk(sChunk, 0, 0, hcH, hcL, WhhHi, WhhLo, m, nb, w, l);

    f32x4 acc00 = {0.f, 0.f, 0.f, 0.f}, acc01 = {0.f, 0.f, 0.f, 0.f};
    f32x4 acc10 = {0.f, 0.f, 0.f, 0.f}, acc11 = {0.f, 0.f, 0.f, 0.f};

    // ---- x-part: gates += x @ Wih^T (3-term split) ----
    #pragma unroll
    for (int ks = 0; ks < 4; ++ks) {
      int k8 = ks * 4 + (l >> 4);
      int ra = 32 * mh + (l & 15), rb = ra + 16;
      int ca = 32 * nh + (l & 15), cb = ca + 16;
      bf16x8 ah0 = ldf(sXHi, ra, k8, 128, 15), ah1 = ldf(sXHi, rb, k8, 128, 15);
      bf16x8 al0 = ldf(sXLo, ra, k8, 128, 15), al1 = ldf(sXLo, rb, k8, 128, 15);
      bf16x8 bh0 = ldf(sWihHi, ca, k8, 128, 15), bh1 = ldf(sWihHi, cb, k8, 128, 15);
      bf16x8 bl0 = ldf(sWihLo, ca, k8, 128, 15), bl1 = ldf(sWihLo, cb, k8, 128, 15);
      MFMA16(ah0, bh0, acc00); MFMA16(al0, bh0, acc00); MFMA16(ah0, bl0, acc00);
      MFMA16(ah0, bh1, acc01); MFMA16(al0, bh1, acc01); MFMA16(ah0, bl1, acc01);
      MFMA16(ah1, bh0, acc10); MFMA16(al1, bh0, acc10); MFMA16(ah1, bl0, acc10);
      MFMA16(ah1, bh1, acc11); MFMA16(al1, bh1, acc11); MFMA16(ah1, bl1, acc11);
    }
    __syncthreads();  // chunk 0 landed (implicit vmcnt drain + barrier)

    // ---- h-part: 8 double-buffered K=64 chunks ----
    int db = 0;
    #pragma unroll 1
    for (int kc = 0; kc < 8; ++kc) {
      if (kc < 7) stage_chunk(sChunk, db ^ 1, kc + 1, hcH, hcL, WhhHi, WhhLo, m, nb, w, l);
      const u16* Ahi = (const u16*)(sChunk + (db * 4 + 0) * 8192);
      const u16* Alo = (const u16*)(sChunk + (db * 4 + 1) * 8192);
      const u16* Bhi = (const u16*)(sChunk + (db * 4 + 2) * 8192);
      const u16* Blo = (const u16*)(sChunk + (db * 4 + 3) * 8192);
      #pragma unroll
      for (int ks = 0; ks < 2; ++ks) {
        int k8 = ks * 4 + (l >> 4);
        int ra = 32 * mh + (l & 15), rb = ra + 16;
        int ca = 32 * nh + (l & 15), cb = ca + 16;
        bf16x8 ah0 = ldf(Ahi, ra, k8, 64, 7), ah1 = ldf(Ahi, rb, k8, 64, 7);
        bf16x8 al0 = ldf(Alo, ra, k8, 64, 7), al1 = ldf(Alo, rb, k8, 64, 7);
        bf16x8 bh0 = ldf(Bhi, ca, k8, 64, 7), bh1 = ldf(Bhi, cb, k8, 64, 7);
        bf16x8 bl0 = ldf(Blo, ca, k8, 64, 7), bl1 = ldf(Blo, cb, k8, 64, 7);
        MFMA16(ah0, bh0, acc00); MFMA16(al0, bh0, acc00); MFMA16(ah0, bl0, acc00);
        MFMA16(ah0, bh1, acc01); MFMA16(al0, bh1, acc01); MFMA16(ah0, bl1, acc01);
        MFMA16(ah1, bh0, acc10); MFMA16(al1, bh0, acc10); MFMA16(ah1, bl0, acc10);
        MFMA16(ah1, bh1, acc11); MFMA16(al1, bh1, acc11); MFMA16(ah1, bl1, acc11);
      }
      __syncthreads();
      db ^= 1;
    }

    // ---- write gate preactivations to LDS (D layout: col=lane&15, row=4*(lane>>4)+q) ----
    {
      int rb0 = 32 * mh + 4 * (l >> 4);
      int cb0 = 32 * nh + (l & 15);
      #pragma unroll
      for (int q = 0; q < 4; ++q) {
        sGates[(rb0 + q) * 64 + cb0]            = acc00[q];
        sGates[(rb0 + q) * 64 + cb0 + 16]       = acc01[q];
        sGates[(rb0 + 16 + q) * 64 + cb0]       = acc10[q];
        sGates[(rb0 + 16 + q) * 64 + cb0 + 16]  = acc11[q];
      }
    }
    __syncthreads();

    // ---- elementwise LSTM update (c persistent in LDS), write split h ----
    #pragma unroll
    for (int it = tid; it < 1024; it += 256) {
      int rr = it >> 4, uu = it & 15;
      float gi = sGates[rr * 64 + uu]      + sBias[uu];
      float gf = sGates[rr * 64 + 16 + uu] + sBias[16 + uu];
      float gg = sGates[rr * 64 + 32 + uu] + sBias[32 + uu];
      float go = sGates[rr * 64 + 48 + uu] + sBias[48 + uu];
      float ii = 1.f / (1.f + __expf(-gi));
      float ff = 1.f / (1.f + __expf(-gf));
      float gG = 1.f - 2.f / (__expf(2.f * gg) + 1.f);
      float oo = 1.f / (1.f + __expf(-go));
      float c = ff * sC[rr * 16 + uu] + ii * gG;
      sC[rr * 16 + uu] = c;
      float h = oo * (1.f - 2.f / (__expf(2.f * c) + 1.f));
      size_t idx = (size_t)(64 * m + rr) * H_ + 16 * nb + uu;
      u16 hb = f2bf(h);
      hnH[idx] = hb;
      hnL[idx] = f2bf(h - bf2f(hb));
      if (t == T_ - 1) hT[idx] = h;
    }

    // ---- row-group barrier (32 wgs), monotonic counter ----
    __threadfence();
    __syncthreads();
    if (tid == 0) {
      __hip_atomic_fetch_add(&bar[m * 16], 1u, __ATOMIC_RELEASE, __HIP_MEMORY_SCOPE_AGENT);
      unsigned target = 32u * (unsigned)(t + 1);
      long fuse = 100000000;
      while (__hip_atomic_load(&bar[m * 16], __ATOMIC_ACQUIRE, __HIP_MEMORY_SCOPE_AGENT) < target) {
        __builtin_amdgcn_s_sleep(2);
        if (--fuse == 0) break;
      }
    }
    __syncthreads();
    __builtin_amdgcn_fence(__ATOMIC_ACQUIRE, "agent");
  }
}

// ---------------- head: z = relu(hT @ W1^T + b1) ----------------
__global__ __launch_bounds__(256) void head1(const float* __restrict__ hT,
                                             const float* __restrict__ W1,
                                             const float* __restrict__ b1,
                                             float* __restrict__ z) {
  __shared__ float sA[64][16];
  __shared__ float sBt[16][64];
  int tx = threadIdx.x & 15, ty = threadIdx.x >> 4;
  int row0 = blockIdx.y * 64, col0 = blockIdx.x * 64;
  float acc[4][4] = {};
  for (int k0 = 0; k0 < H_; k0 += 16) {
    int c = threadIdx.x >> 2, kk4 = (threadIdx.x & 3) * 4;
    float4 av = *(const float4*)(hT + (size_t)(row0 + c) * H_ + k0 + kk4);
    *(float4*)&sA[c][kk4] = av;
    float4 bv = *(const float4*)(W1 + (size_t)(col0 + c) * H_ + k0 + kk4);
    sBt[kk4 + 0][c] = bv.x; sBt[kk4 + 1][c] = bv.y;
    sBt[kk4 + 2][c] = bv.z; sBt[kk4 + 3][c] = bv.w;
    __syncthreads();
    #pragma unroll
    for (int kk = 0; kk < 16; ++kk) {
      float a0 = sA[ty * 4 + 0][kk], a1 = sA[ty * 4 + 1][kk];
      float a2 = sA[ty * 4 + 2][kk], a3 = sA[ty * 4 + 3][kk];
      float b0 = sBt[kk][tx * 4 + 0], b1v = sBt[kk][tx * 4 + 1];
      float b2v = sBt[kk][tx * 4 + 2], b3 = sBt[kk][tx * 4 + 3];
      acc[0][0] += a0 * b0; acc[0][1] += a0 * b1v; acc[0][2] += a0 * b2v; acc[0][3] += a0 * b3;
      acc[1][0] += a1 * b0; acc[1][1] += a1 * b1v; acc[1][2] += a1 * b2v; acc[1][3] += a1 * b3;
      acc[2][0] += a2 * b0; acc[2][1] += a2 * b1v; acc[2][2] += a2 * b2v; acc[2][3] += a2 * b3;
      acc[3][0] += a3 * b0; acc[3][1] += a3 * b1v; acc[3][2] += a3 * b2v; acc[3][3] += a3 * b3;
    }
    __syncthreads();
  }
  #pragma unroll
  for (int i = 0; i < 4; ++i)
    #pragma unroll
    for (int j = 0; j < 4; ++j) {
      int rr = row0 + ty * 4 + i, cc = col0 + tx * 4 + j;
      float v = acc[i][j] + b1[cc];
      z[(size_t)rr * LH_ + cc] = v > 0.f ? v : 0.f;
    }
}

// ---------------- head: out[b] = z[b,:] . W2 + b2 ----------------
__global__ __launch_bounds__(256) void head2(const float* __restrict__ z,
                                             const float* __restrict__ W2,
                                             const float* __restrict__ b2,
                                             float* __restrict__ out) {
  int b = blockIdx.x;
  float p = 0.f;
  for (int j = threadIdx.x; j < LH_; j += 256) p += z[(size_t)b * LH_ + j] * W2[j];
  #pragma unroll
  for (int off = 32; off > 0; off >>= 1) p += __shfl_down(p, off);
  __shared__ float red[4];
  if ((threadIdx.x & 63) == 0) red[threadIdx.x >> 6] = p;
  __syncthreads();
  if (threadIdx.x == 0) out[b] = red[0] + red[1] + red[2] + red[3] + b2[0];
}

// ---------------- launch ----------------
extern "C" void kernel_launch(void* const* d_in, const int* in_sizes, int n_in,
                              void* d_out, int out_size, void* d_ws, size_t ws_size,
                              hipStream_t stream) {
  const float* x    = (const float*)d_in[0];
  const float* Wih  = (const float*)d_in[1];
  const float* Whh  = (const float*)d_in[2];
  const float* bih  = (const float*)d_in[3];
  const float* bhh  = (const float*)d_in[4];
  const float* W1   = (const float*)d_in[5];
  const float* b1   = (const float*)d_in[6];
  const float* W2   = (const float*)d_in[7];
  const float* b2   = (const float*)d_in[8];

  char* ws = (char*)d_ws;
  u16* hHi     = (u16*)(ws + O_HHI);
  u16* hLo     = (u16*)(ws + O_HLO);
  unsigned* bar = (unsigned*)(ws + O_BAR);
  u16* whhHi   = (u16*)(ws + O_WHH_HI);
  u16* whhLo   = (u16*)(ws + O_WHH_LO);
  u16* wihHi   = (u16*)(ws + O_WIH_HI);
  u16* wihLo   = (u16*)(ws + O_WIH_LO);
  float* bias  = (float*)(ws + O_BIAS);
  float* hT    = (float*)(ws + O_HT);
  float* zbuf  = (float*)(ws + O_Z);

  // zero h double-buffers (h0 = c0 = 0) and barrier counters, every call
  (void)hipMemsetAsync(ws, 0, O_MSET, stream);

  prep_weights<<<G_, 128, 0, stream>>>(Wih, Whh, bih, bhh, whhHi, whhLo, wihHi, wihLo, bias);

  (void)hipFuncSetAttribute((const void*)lstm_persistent,
                            hipFuncAttributeMaxDynamicSharedMemorySize, SMEM_BYTES);

  lstm_persistent<<<256, 256, SMEM_BYTES, stream>>>(x, whhHi, whhLo, wihHi, wihLo,
                                                    bias, hHi, hLo, bar, hT);

  head1<<<dim3(LH_ / 64, B_ / 64), 256, 0, stream>>>(hT, W1, b1, zbuf);
  head2<<<B_, 256, 0, stream>>>(zbuf, W2, b2, (float*)d_out);
}

// Round 3
// 23427.588 us; speedup vs baseline: 2.2053x; 2.2053x over previous
//
#include <hip/hip_runtime.h>

typedef unsigned short u16;
typedef unsigned int u32;
typedef __attribute__((ext_vector_type(8))) short bf16x8;
typedef __attribute__((ext_vector_type(4))) float f32x4;

#define B_ 512
#define T_ 1024
#define F_ 128
#define H_ 512
#define G_ 2048
#define LH_ 1024

#define MFMA16(a,b,c) (c) = __builtin_amdgcn_mfma_f32_16x16x32_bf16((a),(b),(c),0,0,0)

__device__ __forceinline__ u16 f2bf(float f) {
  unsigned u = __float_as_uint(f);
  unsigned r = (u + 0x7fffu + ((u >> 16) & 1u)) >> 16;
  return (u16)r;
}
__device__ __forceinline__ float bf2f(u16 h) {
  return __uint_as_float(((unsigned)h) << 16);
}

// ---------------- workspace layout (bytes) ----------------
constexpr size_t O_HPK     = 0;                              // u32 packed h, 2 bufs: 2*512*512*4 = 2 MB
constexpr size_t O_BAR     = O_HPK + (size_t)2 * B_ * H_ * 4;
constexpr size_t O_MSET    = O_BAR + 4096;                   // memset [0, O_MSET) each launch
constexpr size_t O_WHH_HI  = O_MSET;
constexpr size_t O_WHH_LO  = O_WHH_HI + (size_t)G_ * H_ * 2;
constexpr size_t O_WIH_HI  = O_WHH_LO + (size_t)G_ * H_ * 2;
constexpr size_t O_WIH_LO  = O_WIH_HI + (size_t)G_ * F_ * 2;
constexpr size_t O_BIAS    = O_WIH_LO + (size_t)G_ * F_ * 2;
constexpr size_t O_HT      = O_BIAS + (size_t)G_ * 4;
constexpr size_t O_Z       = O_HT + (size_t)B_ * H_ * 4;     // + 512*1024*4

// ---------------- LDS layout (bytes) ----------------
// A slots: 2 x {hi 8KB, lo 8KB} = 32768          ([64 rows][64 k] u16, swizzled)
// B slots: 2 x {hi 16KB, lo 16KB} = 65536        ([128 gcols][64 k] u16, swizzled)
// gates [64][128] f32 = 32768;  c [64][32] f32 = 8192;  bias [128] f32 = 512
constexpr unsigned SM_B     = 32768;
constexpr unsigned SM_GATES = 98304;
constexpr unsigned SM_C     = 131072;
constexpr unsigned SM_BIAS  = 139264;
constexpr unsigned SMEM_BYTES = 139776;

// ---------------- weight prep: permute + split to hi/lo bf16 ----------------
// permuted gate-col P = 128*nb + 32*g + u'  (unit u = 32*nb + u', g in {i,f,g,o})
__global__ void prep_weights(const float* __restrict__ Wih, const float* __restrict__ Whh,
                             const float* __restrict__ bih, const float* __restrict__ bhh,
                             u16* __restrict__ WhhHi, u16* __restrict__ WhhLo,
                             u16* __restrict__ WihHi, u16* __restrict__ WihLo,
                             float* __restrict__ bias) {
  int P = blockIdx.x;
  int nb = P >> 7, g = (P >> 5) & 3, u = P & 31;
  int orig = g * H_ + nb * 32 + u;
  for (int k = threadIdx.x; k < H_; k += 128) {
    float w = Whh[(size_t)orig * H_ + k];
    u16 hi = f2bf(w);
    WhhHi[(size_t)P * H_ + k] = hi;
    WhhLo[(size_t)P * H_ + k] = f2bf(w - bf2f(hi));
  }
  {
    int k = threadIdx.x;
    float w = Wih[(size_t)orig * F_ + k];
    u16 hi = f2bf(w);
    WihHi[(size_t)P * F_ + k] = hi;
    WihLo[(size_t)P * F_ + k] = f2bf(w - bf2f(hi));
  }
  if (threadIdx.x == 0) bias[P] = bih[orig] + bhh[orig];
}

// ---------------- helpers ----------------
__device__ __forceinline__ void gl2lds16(const void* g, void* lds) {
  __builtin_amdgcn_global_load_lds(
      (const __attribute__((address_space(1))) unsigned int*)g,
      (__attribute__((address_space(3))) unsigned int*)lds, 16, 0, 0);
}

// swizzled LDS fragment read: 8 contiguous bf16 at (row, k8*8); slot XORed with row&7
__device__ __forceinline__ bf16x8 ldf(const u16* base, int row, int k8) {
  return *(const bf16x8*)(base + row * 64 + ((k8 ^ (row & 7)) << 3));
}

// ---------------- persistent LSTM kernel ----------------
// grid 128 = 8 row-groups (m = bid>>4) x 16 unit-blocks (nb = bid&15); 512 threads (8 waves)
__global__ __launch_bounds__(512, 1) void lstm_persistent(
    const float* __restrict__ x,
    const u16* __restrict__ WhhHi, const u16* __restrict__ WhhLo,
    const u16* __restrict__ WihHi, const u16* __restrict__ WihLo,
    const float* __restrict__ bias,
    u32* __restrict__ hPk, u32* __restrict__ bar, float* __restrict__ hT) {
  extern __shared__ char smem[];
  float* sGates = (float*)(smem + SM_GATES);
  float* sC     = (float*)(smem + SM_C);
  float* sBias  = (float*)(smem + SM_BIAS);

  const int tid = threadIdx.x;
  const int w = tid >> 6, l = tid & 63;
  const int m  = blockIdx.x >> 4;   // 0..7 (64 batch rows)
  const int nb = blockIdx.x & 15;   // 0..15 (32 units / 128 gate cols)
  const int mh = w & 1, nh = w >> 1;
  const int Pbase = 128 * nb;

  // staging coords
  const int sr = tid >> 3, sk8 = tid & 7;              // 64 rows x 8 k-groups
  const unsigned soff = sr * 64 + ((sk8 ^ (sr & 7)) << 3);  // u16 units, swizzled

  // one-time init
  if (tid < 128) sBias[tid] = bias[Pbase + tid];
  for (int i = tid; i < 2048; i += 512) sC[i] = 0.f;
  __syncthreads();

  #pragma unroll 1
  for (int t = 0; t < T_; ++t) {
    const u32* hcur = hPk + (size_t)(t & 1) * B_ * H_;
    u32* hnxt = hPk + (size_t)((t & 1) ^ 1) * B_ * H_;

    // ---- prologue: stage x chunks 0,1 + Wih chunks 0,1 (independent of h) ----
    #pragma unroll
    for (int ch = 0; ch < 2; ++ch) {
      // x: fp32 -> split bf16, swizzled ds_write
      const float* xs = x + ((size_t)(64 * m + sr) * T_ + t) * F_ + 64 * ch + sk8 * 8;
      float4 v0 = *(const float4*)(xs);
      float4 v1 = *(const float4*)(xs + 4);
      float fv[8] = {v0.x, v0.y, v0.z, v0.w, v1.x, v1.y, v1.z, v1.w};
      bf16x8 hi, lo;
      #pragma unroll
      for (int e = 0; e < 8; ++e) {
        u16 hb = f2bf(fv[e]);
        hi[e] = (short)hb;
        lo[e] = (short)f2bf(fv[e] - bf2f(hb));
      }
      *(bf16x8*)((u16*)(smem + ch * 16384) + soff) = hi;
      *(bf16x8*)((u16*)(smem + ch * 16384 + 8192) + soff) = lo;
      // Wih: async global->LDS, pre-swizzled source, linear dest
      #pragma unroll
      for (int j = 0; j < 2; ++j) {
        int p = w * 16 + j * 8 + (l >> 3);
        int k8 = (l & 7) ^ (p & 7);
        const u16* srcH = WihHi + (size_t)(Pbase + p) * F_ + 64 * ch + k8 * 8;
        const u16* srcL = WihLo + (size_t)(Pbase + p) * F_ + 64 * ch + k8 * 8;
        gl2lds16(srcH, smem + SM_B + ch * 32768 + (w * 16 + j * 8) * 128);
        gl2lds16(srcL, smem + SM_B + ch * 32768 + 16384 + (w * 16 + j * 8) * 128);
      }
    }
    __syncthreads();

    f32x4 acc00 = {0.f,0.f,0.f,0.f}, acc01 = {0.f,0.f,0.f,0.f};
    f32x4 acc10 = {0.f,0.f,0.f,0.f}, acc11 = {0.f,0.f,0.f,0.f};

    // ---- compute x-part (2 chunks) while other wgs may still be finishing ----
    #pragma unroll
    for (int ch = 0; ch < 2; ++ch) {
      const u16* Ahi = (const u16*)(smem + ch * 16384);
      const u16* Alo = (const u16*)(smem + ch * 16384 + 8192);
      const u16* Bhi = (const u16*)(smem + SM_B + ch * 32768);
      const u16* Blo = (const u16*)(smem + SM_B + ch * 32768 + 16384);
      #pragma unroll
      for (int ks = 0; ks < 2; ++ks) {
        int k8 = ks * 4 + (l >> 4);
        int ra = 32 * mh + (l & 15), rb = ra + 16;
        int ca = 32 * nh + (l & 15), cb = ca + 16;
        bf16x8 ah0 = ldf(Ahi, ra, k8), ah1 = ldf(Ahi, rb, k8);
        bf16x8 al0 = ldf(Alo, ra, k8), al1 = ldf(Alo, rb, k8);
        bf16x8 bh0 = ldf(Bhi, ca, k8), bh1 = ldf(Bhi, cb, k8);
        bf16x8 bl0 = ldf(Blo, ca, k8), bl1 = ldf(Blo, cb, k8);
        MFMA16(ah0, bh0, acc00); MFMA16(al0, bh0, acc00); MFMA16(ah0, bl0, acc00);
        MFMA16(ah0, bh1, acc01); MFMA16(al0, bh1, acc01); MFMA16(ah0, bl1, acc01);
        MFMA16(ah1, bh0, acc10); MFMA16(al1, bh0, acc10); MFMA16(ah1, bl0, acc10);
        MFMA16(ah1, bh1, acc11); MFMA16(al1, bh1, acc11); MFMA16(ah1, bl1, acc11);
      }
    }

    // ---- poll: h from step t-1 ready? (relaxed system atomics, NO fences) ----
    if (t > 0 && tid == 0) {
      unsigned tgt = 16u * (unsigned)t;
      long fuse = 400000000;
      while (__hip_atomic_load(&bar[m * 32], __ATOMIC_RELAXED, __HIP_MEMORY_SCOPE_SYSTEM) < tgt) {
        __builtin_amdgcn_s_sleep(2);
        if (--fuse == 0) break;
      }
    }
    __syncthreads();

    // ---- h pipeline: 8 K=64 chunks, double-buffered ----
    u32 hr0[8], hr1[8];
    const u32* hrow = hcur + (size_t)(64 * m + sr) * H_ + sk8 * 8;
    {
      #pragma unroll
      for (int j = 0; j < 8; ++j)
        hr0[j] = __hip_atomic_load(hrow + j, __ATOMIC_RELAXED, __HIP_MEMORY_SCOPE_SYSTEM);
      #pragma unroll
      for (int j = 0; j < 8; ++j)
        hr1[j] = __hip_atomic_load(hrow + 64 + j, __ATOMIC_RELAXED, __HIP_MEMORY_SCOPE_SYSTEM);
      // stage h0 -> slot0, h1 -> slot1 ; Whh0 -> slot0, Whh1 -> slot1
      bf16x8 hi, lo;
      #pragma unroll
      for (int j = 0; j < 8; ++j) { hi[j] = (short)(hr0[j] & 0xffff); lo[j] = (short)(hr0[j] >> 16); }
      *(bf16x8*)((u16*)(smem) + soff) = hi;
      *(bf16x8*)((u16*)(smem + 8192) + soff) = lo;
      #pragma unroll
      for (int j = 0; j < 8; ++j) { hi[j] = (short)(hr1[j] & 0xffff); lo[j] = (short)(hr1[j] >> 16); }
      *(bf16x8*)((u16*)(smem + 16384) + soff) = hi;
      *(bf16x8*)((u16*)(smem + 16384 + 8192) + soff) = lo;
      #pragma unroll
      for (int hc = 0; hc < 2; ++hc) {
        #pragma unroll
        for (int j = 0; j < 2; ++j) {
          int p = w * 16 + j * 8 + (l >> 3);
          int k8 = (l & 7) ^ (p & 7);
          const u16* srcH = WhhHi + (size_t)(Pbase + p) * H_ + 64 * hc + k8 * 8;
          const u16* srcL = WhhLo + (size_t)(Pbase + p) * H_ + 64 * hc + k8 * 8;
          gl2lds16(srcH, smem + SM_B + hc * 32768 + (w * 16 + j * 8) * 128);
          gl2lds16(srcL, smem + SM_B + hc * 32768 + 16384 + (w * 16 + j * 8) * 128);
        }
      }
    }
    __syncthreads();

    #pragma unroll 1
    for (int hc = 0; hc < 8; ++hc) {
      const int s = hc & 1;
      // issue next-next chunk's h loads (consumed at tail of this iter)
      if (hc + 2 < 8) {
        #pragma unroll
        for (int j = 0; j < 8; ++j)
          hr0[j] = __hip_atomic_load(hrow + 64 * (hc + 2) + j, __ATOMIC_RELAXED, __HIP_MEMORY_SCOPE_SYSTEM);
      }
      // compute chunk hc from slot s
      {
        const u16* Ahi = (const u16*)(smem + s * 16384);
        const u16* Alo = (const u16*)(smem + s * 16384 + 8192);
        const u16* Bhi = (const u16*)(smem + SM_B + s * 32768);
        const u16* Blo = (const u16*)(smem + SM_B + s * 32768 + 16384);
        #pragma unroll
        for (int ks = 0; ks < 2; ++ks) {
          int k8 = ks * 4 + (l >> 4);
          int ra = 32 * mh + (l & 15), rb = ra + 16;
          int ca = 32 * nh + (l & 15), cb = ca + 16;
          bf16x8 ah0 = ldf(Ahi, ra, k8), ah1 = ldf(Ahi, rb, k8);
          bf16x8 al0 = ldf(Alo, ra, k8), al1 = ldf(Alo, rb, k8);
          bf16x8 bh0 = ldf(Bhi, ca, k8), bh1 = ldf(Bhi, cb, k8);
          bf16x8 bl0 = ldf(Blo, ca, k8), bl1 = ldf(Blo, cb, k8);
          MFMA16(ah0, bh0, acc00); MFMA16(al0, bh0, acc00); MFMA16(ah0, bl0, acc00);
          MFMA16(ah0, bh1, acc01); MFMA16(al0, bh1, acc01); MFMA16(ah0, bl1, acc01);
          MFMA16(ah1, bh0, acc10); MFMA16(al1, bh0, acc10); MFMA16(ah1, bl0, acc10);
          MFMA16(ah1, bh1, acc11); MFMA16(al1, bh1, acc11); MFMA16(ah1, bl1, acc11);
        }
      }
      __syncthreads();   // done reading slot s
      if (hc + 2 < 8) {
        bf16x8 hi, lo;
        #pragma unroll
        for (int j = 0; j < 8; ++j) { hi[j] = (short)(hr0[j] & 0xffff); lo[j] = (short)(hr0[j] >> 16); }
        *(bf16x8*)((u16*)(smem + s * 16384) + soff) = hi;
        *(bf16x8*)((u16*)(smem + s * 16384 + 8192) + soff) = lo;
        #pragma unroll
        for (int j = 0; j < 2; ++j) {
          int p = w * 16 + j * 8 + (l >> 3);
          int k8 = (l & 7) ^ (p & 7);
          const u16* srcH = WhhHi + (size_t)(Pbase + p) * H_ + 64 * (hc + 2) + k8 * 8;
          const u16* srcL = WhhLo + (size_t)(Pbase + p) * H_ + 64 * (hc + 2) + k8 * 8;
          gl2lds16(srcH, smem + SM_B + s * 32768 + (w * 16 + j * 8) * 128);
          gl2lds16(srcL, smem + SM_B + s * 32768 + 16384 + (w * 16 + j * 8) * 128);
        }
      }
    }

    // ---- gate preactivations to LDS (C/D layout: col=lane&15, row=4*(lane>>4)+q) ----
    {
      int rb0 = 32 * mh + 4 * (l >> 4);
      int cb0 = 32 * nh + (l & 15);
      #pragma unroll
      for (int q = 0; q < 4; ++q) {
        sGates[(rb0 + q) * 128 + cb0]            = acc00[q];
        sGates[(rb0 + q) * 128 + cb0 + 16]       = acc01[q];
        sGates[(rb0 + 16 + q) * 128 + cb0]       = acc10[q];
        sGates[(rb0 + 16 + q) * 128 + cb0 + 16]  = acc11[q];
      }
    }
    __syncthreads();

    // ---- elementwise LSTM update (c persistent in LDS), packed system h store ----
    #pragma unroll
    for (int i = 0; i < 4; ++i) {
      int it = tid + i * 512;
      int rr = it >> 5, uu = it & 31;
      float gi = sGates[rr * 128 + uu]      + sBias[uu];
      float gf = sGates[rr * 128 + 32 + uu] + sBias[32 + uu];
      float gg = sGates[rr * 128 + 64 + uu] + sBias[64 + uu];
      float go = sGates[rr * 128 + 96 + uu] + sBias[96 + uu];
      float ii = 1.f / (1.f + __expf(-gi));
      float ff = 1.f / (1.f + __expf(-gf));
      float gG = 1.f - 2.f / (__expf(2.f * gg) + 1.f);
      float oo = 1.f / (1.f + __expf(-go));
      float c = ff * sC[rr * 32 + uu] + ii * gG;
      sC[rr * 32 + uu] = c;
      float h = oo * (1.f - 2.f / (__expf(2.f * c) + 1.f));
      u16 hb = f2bf(h);
      u16 lb = f2bf(h - bf2f(hb));
      u32 pk = (u32)hb | ((u32)lb << 16);
      size_t idx = (size_t)(64 * m + rr) * H_ + 32 * nb + uu;
      __hip_atomic_store(&hnxt[idx], pk, __ATOMIC_RELAXED, __HIP_MEMORY_SCOPE_SYSTEM);
      if (t == T_ - 1) hT[idx] = h;
    }

    // ---- signal: stores drained, then one relaxed add per wg ----
    asm volatile("s_waitcnt vmcnt(0)" ::: "memory");
    __syncthreads();
    if (tid == 0)
      __hip_atomic_fetch_add(&bar[m * 32], 1u, __ATOMIC_RELAXED, __HIP_MEMORY_SCOPE_SYSTEM);
  }
}

// ---------------- head: z = relu(hT @ W1^T + b1) ----------------
__global__ __launch_bounds__(256) void head1(const float* __restrict__ hT,
                                             const float* __restrict__ W1,
                                             const float* __restrict__ b1,
                                             float* __restrict__ z) {
  __shared__ float sA[64][16];
  __shared__ float sBt[16][64];
  int tx = threadIdx.x & 15, ty = threadIdx.x >> 4;
  int row0 = blockIdx.y * 64, col0 = blockIdx.x * 64;
  float acc[4][4] = {};
  for (int k0 = 0; k0 < H_; k0 += 16) {
    int c = threadIdx.x >> 2, kk4 = (threadIdx.x & 3) * 4;
    float4 av = *(const float4*)(hT + (size_t)(row0 + c) * H_ + k0 + kk4);
    *(float4*)&sA[c][kk4] = av;
    float4 bv = *(const float4*)(W1 + (size_t)(col0 + c) * H_ + k0 + kk4);
    sBt[kk4 + 0][c] = bv.x; sBt[kk4 + 1][c] = bv.y;
    sBt[kk4 + 2][c] = bv.z; sBt[kk4 + 3][c] = bv.w;
    __syncthreads();
    #pragma unroll
    for (int kk = 0; kk < 16; ++kk) {
      float a0 = sA[ty * 4 + 0][kk], a1 = sA[ty * 4 + 1][kk];
      float a2 = sA[ty * 4 + 2][kk], a3 = sA[ty * 4 + 3][kk];
      float b0 = sBt[kk][tx * 4 + 0], b1v = sBt[kk][tx * 4 + 1];
      float b2v = sBt[kk][tx * 4 + 2], b3 = sBt[kk][tx * 4 + 3];
      acc[0][0] += a0 * b0; acc[0][1] += a0 * b1v; acc[0][2] += a0 * b2v; acc[0][3] += a0 * b3;
      acc[1][0] += a1 * b0; acc[1][1] += a1 * b1v; acc[1][2] += a1 * b2v; acc[1][3] += a1 * b3;
      acc[2][0] += a2 * b0; acc[2][1] += a2 * b1v; acc[2][2] += a2 * b2v; acc[2][3] += a2 * b3;
      acc[3][0] += a3 * b0; acc[3][1] += a3 * b1v; acc[3][2] += a3 * b2v; acc[3][3] += a3 * b3;
    }
    __syncthreads();
  }
  #pragma unroll
  for (int i = 0; i < 4; ++i)
    #pragma unroll
    for (int j = 0; j < 4; ++j) {
      int rr = row0 + ty * 4 + i, cc = col0 + tx * 4 + j;
      float v = acc[i][j] + b1[cc];
      z[(size_t)rr * LH_ + cc] = v > 0.f ? v : 0.f;
    }
}

// ---------------- head: out[b] = z[b,:] . W2 + b2 ----------------
__global__ __launch_bounds__(256) void head2(const float* __restrict__ z,
                                             const float* __restrict__ W2,
                                             const float* __restrict__ b2,
                                             float* __restrict__ out) {
  int b = blockIdx.x;
  float p = 0.f;
  for (int j = threadIdx.x; j < LH_; j += 256) p += z[(size_t)b * LH_ + j] * W2[j];
  #pragma unroll
  for (int off = 32; off > 0; off >>= 1) p += __shfl_down(p, off);
  __shared__ float red[4];
  if ((threadIdx.x & 63) == 0) red[threadIdx.x >> 6] = p;
  __syncthreads();
  if (threadIdx.x == 0) out[b] = red[0] + red[1] + red[2] + red[3] + b2[0];
}

// ---------------- launch ----------------
extern "C" void kernel_launch(void* const* d_in, const int* in_sizes, int n_in,
                              void* d_out, int out_size, void* d_ws, size_t ws_size,
                              hipStream_t stream) {
  const float* x    = (const float*)d_in[0];
  const float* Wih  = (const float*)d_in[1];
  const float* Whh  = (const float*)d_in[2];
  const float* bih  = (const float*)d_in[3];
  const float* bhh  = (const float*)d_in[4];
  const float* W1   = (const float*)d_in[5];
  const float* b1   = (const float*)d_in[6];
  const float* W2   = (const float*)d_in[7];
  const float* b2   = (const float*)d_in[8];

  char* ws = (char*)d_ws;
  u32* hPk      = (u32*)(ws + O_HPK);
  u32* bar      = (u32*)(ws + O_BAR);
  u16* whhHi    = (u16*)(ws + O_WHH_HI);
  u16* whhLo    = (u16*)(ws + O_WHH_LO);
  u16* wihHi    = (u16*)(ws + O_WIH_HI);
  u16* wihLo    = (u16*)(ws + O_WIH_LO);
  float* bias   = (float*)(ws + O_BIAS);
  float* hT     = (float*)(ws + O_HT);
  float* zbuf   = (float*)(ws + O_Z);

  // zero h double-buffers (h0 = 0) and barrier counters, every call
  (void)hipMemsetAsync(ws, 0, O_MSET, stream);

  prep_weights<<<G_, 128, 0, stream>>>(Wih, Whh, bih, bhh, whhHi, whhLo, wihHi, wihLo, bias);

  (void)hipFuncSetAttribute((const void*)lstm_persistent,
                            hipFuncAttributeMaxDynamicSharedMemorySize, SMEM_BYTES);

  lstm_persistent<<<128, 512, SMEM_BYTES, stream>>>(x, whhHi, whhLo, wihHi, wihLo,
                                                    bias, hPk, bar, hT);

  head1<<<dim3(LH_ / 64, B_ / 64), 256, 0, stream>>>(hT, W1, b1, zbuf);
  head2<<<B_, 256, 0, stream>>>(zbuf, W2, b2, (float*)d_out);
}

// Round 5
// 12312.839 us; speedup vs baseline: 4.1961x; 1.9027x over previous
//
#include <hip/hip_runtime.h>

typedef unsigned short u16;
typedef unsigned int u32;
typedef __attribute__((ext_vector_type(8))) short bf16x8;
typedef __attribute__((ext_vector_type(4))) float f32x4;
typedef __attribute__((ext_vector_type(4))) unsigned int u32x4;

#define B_ 512
#define T_ 1024
#define F_ 128
#define H_ 512
#define G_ 2048
#define LH_ 1024

#define MFMA16(a,b,c) (c) = __builtin_amdgcn_mfma_f32_16x16x32_bf16((a),(b),(c),0,0,0)

__device__ __forceinline__ u16 f2bf(float f) {
  unsigned u = __float_as_uint(f);
  unsigned r = (u + 0x7fffu + ((u >> 16) & 1u)) >> 16;
  return (u16)r;
}
__device__ __forceinline__ float bf2f(u16 h) {
  return __uint_as_float(((unsigned)h) << 16);
}

// ---------------- workspace layout (bytes) ----------------
constexpr size_t O_HPK     = 0;                              // u32 packed h, 2 bufs: 2 MB
constexpr size_t O_BAR     = O_HPK + (size_t)2 * B_ * H_ * 4;
constexpr size_t O_MSET    = O_BAR + 4096;                   // memset [0, O_MSET) each launch
constexpr size_t O_WHH_HI  = O_MSET;
constexpr size_t O_WHH_LO  = O_WHH_HI + (size_t)G_ * H_ * 2;
constexpr size_t O_WIH_HI  = O_WHH_LO + (size_t)G_ * H_ * 2;
constexpr size_t O_WIH_LO  = O_WIH_HI + (size_t)G_ * F_ * 2;
constexpr size_t O_BIAS    = O_WIH_LO + (size_t)G_ * F_ * 2;
constexpr size_t O_HT      = O_BIAS + (size_t)G_ * 4;
constexpr size_t O_Z       = O_HT + (size_t)B_ * H_ * 4;

// ---------------- LDS layout ----------------
constexpr unsigned SM_WHH_LO = 65536;    // sWhhHi [64][512] u16 swizzled at 0
constexpr unsigned SM_GATES  = 131072;   // f32[64][64]
constexpr unsigned SM_C      = 147456;   // f32[64][16]
constexpr unsigned SM_BIAS   = 151552;   // f32[64]
constexpr unsigned SMEM_BYTES = 151808;

// ---------------- weight prep: permute + split to hi/lo bf16 ----------------
// permuted gate-col P = 64*nb + 16*g + u'  (unit u = 16*nb + u', g in {i,f,g,o})
__global__ void prep_weights(const float* __restrict__ Wih, const float* __restrict__ Whh,
                             const float* __restrict__ bih, const float* __restrict__ bhh,
                             u16* __restrict__ WhhHi, u16* __restrict__ WhhLo,
                             u16* __restrict__ WihHi, u16* __restrict__ WihLo,
                             float* __restrict__ bias) {
  int P = blockIdx.x;
  int nb = P >> 6, g = (P >> 4) & 3, u = P & 15;
  int orig = g * H_ + (nb << 4) + u;
  for (int k = threadIdx.x; k < H_; k += 128) {
    float w = Whh[(size_t)orig * H_ + k];
    u16 hi = f2bf(w);
    WhhHi[(size_t)P * H_ + k] = hi;
    WhhLo[(size_t)P * H_ + k] = f2bf(w - bf2f(hi));
  }
  {
    int k = threadIdx.x;
    float w = Wih[(size_t)orig * F_ + k];
    u16 hi = f2bf(w);
    WihHi[(size_t)P * F_ + k] = hi;
    WihLo[(size_t)P * F_ + k] = f2bf(w - bf2f(hi));
  }
  if (threadIdx.x == 0) bias[P] = bih[orig] + bhh[orig];
}

// ---------------- helpers ----------------
// system-coherent 16B load; data valid only after matching s_waitcnt vmcnt
__device__ __forceinline__ u32x4 ald16(const u32* p) {
  u32x4 r;
  asm volatile("global_load_dwordx4 %0, %1, off sc0 sc1" : "=&v"(r) : "v"(p));
  return r;
}

__device__ __forceinline__ void unpack(u32x4 a, u32x4 b, bf16x8& hi, bf16x8& lo) {
  #pragma unroll
  for (int j = 0; j < 4; ++j) { hi[j] = (short)(a[j] & 0xffffu); lo[j] = (short)(a[j] >> 16); }
  #pragma unroll
  for (int j = 0; j < 4; ++j) { hi[4 + j] = (short)(b[j] & 0xffffu); lo[4 + j] = (short)(b[j] >> 16); }
}

__device__ __forceinline__ void cvt8(float4 a, float4 b, bf16x8& hi, bf16x8& lo) {
  float f[8] = {a.x, a.y, a.z, a.w, b.x, b.y, b.z, b.w};
  #pragma unroll
  for (int j = 0; j < 8; ++j) {
    u16 h = f2bf(f[j]);
    hi[j] = (short)h;
    lo[j] = (short)f2bf(f[j] - bf2f(h));
  }
}

// swizzled B-fragment read from resident Whh slice: row-stride 512 u16, slot k8^(row&7)
__device__ __forceinline__ bf16x8 ldB(const u16* base, int r, int k8) {
  return *(const bf16x8*)(base + r * 512 + ((k8 ^ (r & 7)) << 3));
}

// ---------------- persistent LSTM kernel ----------------
// grid 256 = 8 row-groups (m = bid&7, XCD-aligned) x 32 unit-blocks (nb = bid>>3)
// 512 threads = 8 waves = 4 row-tiles x 2 col-pairs
__global__ __launch_bounds__(512, 2) void lstm_persistent(
    const float* __restrict__ x,
    const u16* __restrict__ WhhHi, const u16* __restrict__ WhhLo,
    const u16* __restrict__ WihHi, const u16* __restrict__ WihLo,
    const float* __restrict__ bias,
    u32* __restrict__ hPk, u32* __restrict__ bar, float* __restrict__ hT) {
  extern __shared__ char smem[];
  u16* sWhhHi   = (u16*)(smem);
  u16* sWhhLo   = (u16*)(smem + SM_WHH_LO);
  float* sGates = (float*)(smem + SM_GATES);
  float* sC     = (float*)(smem + SM_C);
  float* sBias  = (float*)(smem + SM_BIAS);

  const int tid = threadIdx.x;
  const int w = tid >> 6, l = tid & 63;
  const int m  = blockIdx.x & 7;    // row group 0..7 (64 batch rows), XCD-aligned
  const int nb = blockIdx.x >> 3;   // unit block 0..31 (16 units / 64 gate cols)
  const int rt = w >> 1, cp = w & 1;
  const int Pbase = 64 * nb;
  const int l15 = l & 15, l4 = l >> 4;

  // ---- one-time: fill resident Whh slice (swizzled), bias, c=0 ----
  #pragma unroll
  for (int i = 0; i < 8; ++i) {
    int idx = tid + i * 512;
    int r = idx >> 6, k8 = idx & 63;
    unsigned dst = r * 512 + ((k8 ^ (r & 7)) << 3);
    *(bf16x8*)(sWhhHi + dst) = *(const bf16x8*)(WhhHi + (size_t)(Pbase + r) * H_ + k8 * 8);
    *(bf16x8*)(sWhhLo + dst) = *(const bf16x8*)(WhhLo + (size_t)(Pbase + r) * H_ + k8 * 8);
  }
  if (tid < 64) sBias[tid] = bias[Pbase + tid];
  for (int i = tid; i < 1024; i += 512) sC[i] = 0.f;

  // ---- one-time: Wih fragments into registers (2 col-tiles x 4 k-chunks, hi+lo) ----
  bf16x8 wfh[2][4], wfl[2][4];
  #pragma unroll
  for (int tt = 0; tt < 2; ++tt) {
    #pragma unroll
    for (int ch = 0; ch < 4; ++ch) {
      int gcol = 16 * (2 * cp + tt) + l15;
      int k8 = ch * 4 + l4;
      wfh[tt][ch] = *(const bf16x8*)(WihHi + (size_t)(Pbase + gcol) * F_ + k8 * 8);
      wfl[tt][ch] = *(const bf16x8*)(WihLo + (size_t)(Pbase + gcol) * F_ + k8 * 8);
    }
  }
  __syncthreads();

  const int arow = 64 * m + 16 * rt + l15;   // this lane's A row (batch row)
  const float* xrow0 = x + (size_t)arow * T_ * F_ + 8 * l4;
  const int br0 = 16 * (2 * cp) + l15;       // B rows for col-tile 0 / 1
  const int br1 = br0 + 16;

  #pragma unroll 1
  for (int t = 0; t < T_; ++t) {
    const u32* hcur = hPk + (size_t)(t & 1) * B_ * H_;
    u32* hnxt = hPk + (size_t)((t & 1) ^ 1) * B_ * H_;

    f32x4 acc0 = {0.f, 0.f, 0.f, 0.f}, acc1 = {0.f, 0.f, 0.f, 0.f};

    // ---- x-part: gates += x @ Wih^T (3-term split), Wih from registers ----
    {
      const float* xr = xrow0 + (size_t)t * F_;
      #pragma unroll
      for (int ch = 0; ch < 4; ++ch) {
        float4 va = *(const float4*)(xr + ch * 32);
        float4 vb = *(const float4*)(xr + ch * 32 + 4);
        bf16x8 xh, xl;
        cvt8(va, vb, xh, xl);
        MFMA16(xh, wfh[0][ch], acc0); MFMA16(xl, wfh[0][ch], acc0); MFMA16(xh, wfl[0][ch], acc0);
        MFMA16(xh, wfh[1][ch], acc1); MFMA16(xl, wfh[1][ch], acc1); MFMA16(xh, wfl[1][ch], acc1);
      }
    }

    // ---- poll: h from step t-1 ready? (relaxed system atomics, no fences) ----
    if (t > 0 && tid == 0) {
      unsigned tgt = 32u * (unsigned)t;
      long fuse = 400000000;
      while (__hip_atomic_load(&bar[m * 16], __ATOMIC_RELAXED, __HIP_MEMORY_SCOPE_SYSTEM) < tgt) {
        __builtin_amdgcn_s_sleep(2);
        if (--fuse == 0) break;
      }
    }
    __syncthreads();

    // ---- h-part: 16 K=32 chunks; A direct-to-register, 4-slot / 3-deep pipeline ----
    if (t > 0) {
      const u32* hrow = hcur + (size_t)arow * H_ + 8 * l4;
      u32x4 Aa[4], Ab[4];
      #pragma unroll
      for (int ch = 0; ch < 3; ++ch) {
        Aa[ch] = ald16(hrow + ch * 32);
        Ab[ch] = ald16(hrow + ch * 32 + 4);
      }
      #pragma unroll
      for (int ch = 0; ch < 16; ++ch) {
        if (ch + 3 < 16) {
          Aa[(ch + 3) & 3] = ald16(hrow + (ch + 3) * 32);
          Ab[(ch + 3) & 3] = ald16(hrow + (ch + 3) * 32 + 4);
        }
        if (ch < 13)       asm volatile("s_waitcnt vmcnt(6)");
        else if (ch == 13) asm volatile("s_waitcnt vmcnt(4)");
        else if (ch == 14) asm volatile("s_waitcnt vmcnt(2)");
        else               asm volatile("s_waitcnt vmcnt(0)");
        __builtin_amdgcn_sched_barrier(0);
        bf16x8 ah, al;
        unpack(Aa[ch & 3], Ab[ch & 3], ah, al);
        int k8 = ch * 4 + l4;
        bf16x8 bh0 = ldB(sWhhHi, br0, k8), bl0 = ldB(sWhhLo, br0, k8);
        bf16x8 bh1 = ldB(sWhhHi, br1, k8), bl1 = ldB(sWhhLo, br1, k8);
        MFMA16(ah, bh0, acc0); MFMA16(al, bh0, acc0); MFMA16(ah, bl0, acc0);
        MFMA16(ah, bh1, acc1); MFMA16(al, bh1, acc1); MFMA16(ah, bl1, acc1);
      }
    }

    // ---- gate preactivations to LDS (D layout: col=lane&15, row=4*(lane>>4)+q) ----
    {
      int gr = 16 * rt + 4 * l4;
      int gc = 32 * cp + l15;
      #pragma unroll
      for (int q = 0; q < 4; ++q) {
        sGates[(gr + q) * 64 + gc]      = acc0[q];
        sGates[(gr + q) * 64 + gc + 16] = acc1[q];
      }
    }
    __syncthreads();

    // ---- elementwise LSTM update (c persistent in LDS), packed system h store ----
    #pragma unroll
    for (int i = 0; i < 2; ++i) {
      int it = tid + i * 512;
      int rr = it >> 4, uu = it & 15;
      float gi = sGates[rr * 64 + uu]      + sBias[uu];
      float gf = sGates[rr * 64 + 16 + uu] + sBias[16 + uu];
      float gg = sGates[rr * 64 + 32 + uu] + sBias[32 + uu];
      float go = sGates[rr * 64 + 48 + uu] + sBias[48 + uu];
      float ii = 1.f / (1.f + __expf(-gi));
      float ff = 1.f / (1.f + __expf(-gf));
      float gG = 1.f - 2.f / (__expf(2.f * gg) + 1.f);
      float oo = 1.f / (1.f + __expf(-go));
      float c = ff * sC[rr * 16 + uu] + ii * gG;
      sC[rr * 16 + uu] = c;
      float h = oo * (1.f - 2.f / (__expf(2.f * c) + 1.f));
      u16 hb = f2bf(h);
      u16 lb = f2bf(h - bf2f(hb));
      u32 pk = (u32)hb | ((u32)lb << 16);
      size_t idx = (size_t)(64 * m + rr) * H_ + 16 * nb + uu;
      __hip_atomic_store(&hnxt[idx], pk, __ATOMIC_RELAXED, __HIP_MEMORY_SCOPE_SYSTEM);
      if (t == T_ - 1) hT[idx] = h;
    }

    // ---- signal: stores drained, then one relaxed add per wg ----
    asm volatile("s_waitcnt vmcnt(0)" ::: "memory");
    __syncthreads();
    if (tid == 0)
      __hip_atomic_fetch_add(&bar[m * 16], 1u, __ATOMIC_RELAXED, __HIP_MEMORY_SCOPE_SYSTEM);
  }
}

// ---------------- head: z = relu(hT @ W1^T + b1) ----------------
__global__ __launch_bounds__(256) void head1(const float* __restrict__ hT,
                                             const float* __restrict__ W1,
                                             const float* __restrict__ b1,
                                             float* __restrict__ z) {
  __shared__ float sA[64][16];
  __shared__ float sBt[16][64];
  int tx = threadIdx.x & 15, ty = threadIdx.x >> 4;
  int row0 = blockIdx.y * 64, col0 = blockIdx.x * 64;
  float acc[4][4] = {};
  for (int k0 = 0; k0 < H_; k0 += 16) {
    int c = threadIdx.x >> 2, kk4 = (threadIdx.x & 3) * 4;
    float4 av = *(const float4*)(hT + (size_t)(row0 + c) * H_ + k0 + kk4);
    *(float4*)&sA[c][kk4] = av;
    float4 bv = *(const float4*)(W1 + (size_t)(col0 + c) * H_ + k0 + kk4);
    sBt[kk4 + 0][c] = bv.x; sBt[kk4 + 1][c] = bv.y;
    sBt[kk4 + 2][c] = bv.z; sBt[kk4 + 3][c] = bv.w;
    __syncthreads();
    #pragma unroll
    for (int kk = 0; kk < 16; ++kk) {
      float a0 = sA[ty * 4 + 0][kk], a1 = sA[ty * 4 + 1][kk];
      float a2 = sA[ty * 4 + 2][kk], a3 = sA[ty * 4 + 3][kk];
      float b0 = sBt[kk][tx * 4 + 0], b1v = sBt[kk][tx * 4 + 1];
      float b2v = sBt[kk][tx * 4 + 2], b3 = sBt[kk][tx * 4 + 3];
      acc[0][0] += a0 * b0; acc[0][1] += a0 * b1v; acc[0][2] += a0 * b2v; acc[0][3] += a0 * b3;
      acc[1][0] += a1 * b0; acc[1][1] += a1 * b1v; acc[1][2] += a1 * b2v; acc[1][3] += a1 * b3;
      acc[2][0] += a2 * b0; acc[2][1] += a2 * b1v; acc[2][2] += a2 * b2v; acc[2][3] += a2 * b3;
      acc[3][0] += a3 * b0; acc[3][1] += a3 * b1v; acc[3][2] += a3 * b2v; acc[3][3] += a3 * b3;
    }
    __syncthreads();
  }
  #pragma unroll
  for (int i = 0; i < 4; ++i)
    #pragma unroll
    for (int j = 0; j < 4; ++j) {
      int rr = row0 + ty * 4 + i, cc = col0 + tx * 4 + j;
      float v = acc[i][j] + b1[cc];
      z[(size_t)rr * LH_ + cc] = v > 0.f ? v : 0.f;
    }
}

// ---------------- head: out[b] = z[b,:] . W2 + b2 ----------------
__global__ __launch_bounds__(256) void head2(const float* __restrict__ z,
                                             const float* __restrict__ W2,
                                             const float* __restrict__ b2,
                                             float* __restrict__ out) {
  int b = blockIdx.x;
  float p = 0.f;
  for (int j = threadIdx.x; j < LH_; j += 256) p += z[(size_t)b * LH_ + j] * W2[j];
  #pragma unroll
  for (int off = 32; off > 0; off >>= 1) p += __shfl_down(p, off);
  __shared__ float red[4];
  if ((threadIdx.x & 63) == 0) red[threadIdx.x >> 6] = p;
  __syncthreads();
  if (threadIdx.x == 0) out[b] = red[0] + red[1] + red[2] + red[3] + b2[0];
}

// ---------------- launch ----------------
extern "C" void kernel_launch(void* const* d_in, const int* in_sizes, int n_in,
                              void* d_out, int out_size, void* d_ws, size_t ws_size,
                              hipStream_t stream) {
  const float* x    = (const float*)d_in[0];
  const float* Wih  = (const float*)d_in[1];
  const float* Whh  = (const float*)d_in[2];
  const float* bih  = (const float*)d_in[3];
  const float* bhh  = (const float*)d_in[4];
  const float* W1   = (const float*)d_in[5];
  const float* b1   = (const float*)d_in[6];
  const float* W2   = (const float*)d_in[7];
  const float* b2   = (const float*)d_in[8];

  char* ws = (char*)d_ws;
  u32* hPk      = (u32*)(ws + O_HPK);
  u32* bar      = (u32*)(ws + O_BAR);
  u16* whhHi    = (u16*)(ws + O_WHH_HI);
  u16* whhLo    = (u16*)(ws + O_WHH_LO);
  u16* wihHi    = (u16*)(ws + O_WIH_HI);
  u16* wihLo    = (u16*)(ws + O_WIH_LO);
  float* bias   = (float*)(ws + O_BIAS);
  float* hT     = (float*)(ws + O_HT);
  float* zbuf   = (float*)(ws + O_Z);

  // zero h double-buffers (h0 = 0) and barrier counters, every call
  (void)hipMemsetAsync(ws, 0, O_MSET, stream);

  prep_weights<<<G_, 128, 0, stream>>>(Wih, Whh, bih, bhh, whhHi, whhLo, wihHi, wihLo, bias);

  (void)hipFuncSetAttribute((const void*)lstm_persistent,
                            hipFuncAttributeMaxDynamicSharedMemorySize, SMEM_BYTES);

  lstm_persistent<<<256, 512, SMEM_BYTES, stream>>>(x, whhHi, whhLo, wihHi, wihLo,
                                                    bias, hPk, bar, hT);

  head1<<<dim3(LH_ / 64, B_ / 64), 256, 0, stream>>>(hT, W1, b1, zbuf);
  head2<<<B_, 256, 0, stream>>>(zbuf, W2, b2, (float*)d_out);
}

// Round 7
// 10875.596 us; speedup vs baseline: 4.7506x; 1.1322x over previous
//
#include <hip/hip_runtime.h>

typedef unsigned short u16;
typedef unsigned int u32;
typedef __attribute__((ext_vector_type(8))) short bf16x8;
typedef __attribute__((ext_vector_type(4))) float f32x4;
typedef __attribute__((ext_vector_type(4))) unsigned int u32x4;

#define B_ 512
#define T_ 1024
#define F_ 128
#define H_ 512
#define G_ 2048
#define LH_ 1024

#define MFMA16(a,b,c) (c) = __builtin_amdgcn_mfma_f32_16x16x32_bf16((a),(b),(c),0,0,0)

__device__ __forceinline__ u16 f2bf(float f) {
  unsigned u = __float_as_uint(f);
  unsigned r = (u + 0x7fffu + ((u >> 16) & 1u)) >> 16;
  return (u16)r;
}
__device__ __forceinline__ float bf2f(u16 h) {
  return __uint_as_float(((unsigned)h) << 16);
}

// ---------------- workspace layout (bytes) ----------------
constexpr size_t O_HPK     = 0;                               // u32 packed h, 2 bufs: 2 MB
constexpr size_t O_FL      = O_HPK + (size_t)2 * B_ * H_ * 4; // per-producer step flags
constexpr size_t O_MSET    = O_FL + 4096;                     // memset [0, O_MSET) each launch
constexpr size_t O_WHH_HI  = O_MSET;
constexpr size_t O_WHH_LO  = O_WHH_HI + (size_t)G_ * H_ * 2;
constexpr size_t O_WIH_HI  = O_WHH_LO + (size_t)G_ * H_ * 2;
constexpr size_t O_WIH_LO  = O_WIH_HI + (size_t)G_ * F_ * 2;
constexpr size_t O_BIAS    = O_WIH_LO + (size_t)G_ * F_ * 2;
constexpr size_t O_HT      = O_BIAS + (size_t)G_ * 4;
constexpr size_t O_Z       = O_HT + (size_t)B_ * H_ * 4;

// ---------------- LDS layout ----------------
constexpr unsigned SM_WHH_LO = 65536;    // sWhhHi [64][512] u16 swizzled at 0
constexpr unsigned SM_GATES  = 131072;   // f32[64][65] padded stride
constexpr unsigned SM_C      = 147712;   // f32[64][16]
constexpr unsigned SM_BIAS   = 151808;   // f32[64]
constexpr unsigned SMEM_BYTES = 152064;

// ---------------- weight prep: permute + split to hi/lo bf16 ----------------
// permuted gate-col P = 64*nb + 16*g + u'  (unit u = 16*nb + u', g in {i,f,g,o})
__global__ void prep_weights(const float* __restrict__ Wih, const float* __restrict__ Whh,
                             const float* __restrict__ bih, const float* __restrict__ bhh,
                             u16* __restrict__ WhhHi, u16* __restrict__ WhhLo,
                             u16* __restrict__ WihHi, u16* __restrict__ WihLo,
                             float* __restrict__ bias) {
  int P = blockIdx.x;
  int nb = P >> 6, g = (P >> 4) & 3, u = P & 15;
  int orig = g * H_ + (nb << 4) + u;
  for (int k = threadIdx.x; k < H_; k += 128) {
    float w = Whh[(size_t)orig * H_ + k];
    u16 hi = f2bf(w);
    WhhHi[(size_t)P * H_ + k] = hi;
    WhhLo[(size_t)P * H_ + k] = f2bf(w - bf2f(hi));
  }
  {
    int k = threadIdx.x;
    float w = Wih[(size_t)orig * F_ + k];
    u16 hi = f2bf(w);
    WihHi[(size_t)P * F_ + k] = hi;
    WihLo[(size_t)P * F_ + k] = f2bf(w - bf2f(hi));
  }
  if (threadIdx.x == 0) bias[P] = bih[orig] + bhh[orig];
}

// ---------------- helpers ----------------
// system-coherent 16B load; data valid only after matching s_waitcnt vmcnt
__device__ __forceinline__ u32x4 ald16(const u32* p) {
  u32x4 r;
  asm volatile("global_load_dwordx4 %0, %1, off sc0 sc1" : "=&v"(r) : "v"(p));
  return r;
}
// plain cacheable 16B load (x prefetch), issue point pinned
__device__ __forceinline__ u32x4 pld16(const float* p) {
  u32x4 r;
  asm volatile("global_load_dwordx4 %0, %1, off" : "=&v"(r) : "v"(p));
  return r;
}

__device__ __forceinline__ void unpack(u32x4 a, u32x4 b, bf16x8& hi, bf16x8& lo) {
  #pragma unroll
  for (int j = 0; j < 4; ++j) { hi[j] = (short)(a[j] & 0xffffu); lo[j] = (short)(a[j] >> 16); }
  #pragma unroll
  for (int j = 0; j < 4; ++j) { hi[4 + j] = (short)(b[j] & 0xffffu); lo[4 + j] = (short)(b[j] >> 16); }
}

__device__ __forceinline__ void cvt8(u32x4 a, u32x4 b, bf16x8& hi, bf16x8& lo) {
  #pragma unroll
  for (int j = 0; j < 8; ++j) {
    float f = __uint_as_float(j < 4 ? a[j] : b[j - 4]);
    u16 h = f2bf(f);
    hi[j] = (short)h;
    lo[j] = (short)f2bf(f - bf2f(h));
  }
}

__device__ __forceinline__ bf16x8 ldB(const u16* base, int r, int k8) {
  return *(const bf16x8*)(base + r * 512 + ((k8 ^ (r & 7)) << 3));
}

// ---------------- persistent LSTM kernel ----------------
// grid 256 = 8 row-groups (m = bid&7) x 32 unit-blocks (nb = bid>>3); 512 threads
__global__ __launch_bounds__(512, 2) void lstm_persistent(
    const float* __restrict__ x,
    const u16* __restrict__ WhhHi, const u16* __restrict__ WhhLo,
    const u16* __restrict__ WihHi, const u16* __restrict__ WihLo,
    const float* __restrict__ bias,
    u32* __restrict__ hPk, u32* __restrict__ fl, float* __restrict__ hT) {
  extern __shared__ char smem[];
  u16* sWhhHi   = (u16*)(smem);
  u16* sWhhLo   = (u16*)(smem + SM_WHH_LO);
  float* sGates = (float*)(smem + SM_GATES);
  float* sC     = (float*)(smem + SM_C);
  float* sBias  = (float*)(smem + SM_BIAS);

  const int tid = threadIdx.x;
  const int w = tid >> 6, l = tid & 63;
  const int m  = blockIdx.x & 7;
  const int nb = blockIdx.x >> 3;
  const int rt = w >> 1, cp = w & 1;
  const int Pbase = 64 * nb;
  const int l15 = l & 15, l4 = l >> 4;

  // ---- one-time: resident Whh slice (swizzled), bias, c=0 ----
  #pragma unroll
  for (int i = 0; i < 8; ++i) {
    int idx = tid + i * 512;
    int r = idx >> 6, k8 = idx & 63;
    unsigned dst = r * 512 + ((k8 ^ (r & 7)) << 3);
    *(bf16x8*)(sWhhHi + dst) = *(const bf16x8*)(WhhHi + (size_t)(Pbase + r) * H_ + k8 * 8);
    *(bf16x8*)(sWhhLo + dst) = *(const bf16x8*)(WhhLo + (size_t)(Pbase + r) * H_ + k8 * 8);
  }
  if (tid < 64) sBias[tid] = bias[Pbase + tid];
  for (int i = tid; i < 1024; i += 512) sC[i] = 0.f;

  // ---- one-time: Wih fragments into registers ----
  bf16x8 wfh[2][4], wfl[2][4];
  #pragma unroll
  for (int tt = 0; tt < 2; ++tt)
    #pragma unroll
    for (int ch = 0; ch < 4; ++ch) {
      int gcol = 16 * (2 * cp + tt) + l15;
      int k8 = ch * 4 + l4;
      wfh[tt][ch] = *(const bf16x8*)(WihHi + (size_t)(Pbase + gcol) * F_ + k8 * 8);
      wfl[tt][ch] = *(const bf16x8*)(WihLo + (size_t)(Pbase + gcol) * F_ + k8 * 8);
    }
  __syncthreads();

  const int arow = 64 * m + 16 * rt + l15;
  const float* xrow0 = x + (size_t)arow * T_ * F_ + 8 * l4;
  const int br0 = 32 * cp + l15;
  const int br1 = br0 + 16;

  // prologue: x(0) prefetch into registers, drained before loop
  u32x4 xa[4], xb[4];
  #pragma unroll
  for (int ch = 0; ch < 4; ++ch) {
    xa[ch] = pld16(xrow0 + ch * 32);
    xb[ch] = pld16(xrow0 + ch * 32 + 4);
  }
  asm volatile("s_waitcnt vmcnt(0)" ::: "memory");

  #pragma unroll 1
  for (int t = 0; t < T_; ++t) {
    const u32* hcur = hPk + (size_t)(t & 1) * B_ * H_;
    u32* hnxt = hPk + (size_t)((t & 1) ^ 1) * B_ * H_;

    f32x4 acc0 = {0.f, 0.f, 0.f, 0.f}, acc1 = {0.f, 0.f, 0.f, 0.f};

    // ---- poll per-producer flags (parallel, lanes 0..31 of wave 0) ----
    if (t > 0) {
      if (tid < 32) {
        const u32* fp = fl + m * 32 + tid;
        long fuse = 400000000;
        while (__hip_atomic_load(fp, __ATOMIC_RELAXED, __HIP_MEMORY_SCOPE_SYSTEM) < (u32)t) {
          __builtin_amdgcn_s_sleep(1);
          if (--fuse == 0) break;
        }
      }
      __syncthreads();
    }

    // ---- issue first half of h loads (chunks 0..7, 16 loads) ----
    u32x4 Aa[8], Ab[8];
    const u32* hrow = hcur + (size_t)arow * H_ + 8 * l4;
    if (t > 0) {
      #pragma unroll
      for (int c = 0; c < 8; ++c) {
        Aa[c] = ald16(hrow + c * 32);
        Ab[c] = ald16(hrow + c * 32 + 4);
      }
    }

    // ---- x-part from prefetched registers (overlaps h-load flight) ----
    #pragma unroll
    for (int ch = 0; ch < 4; ++ch) {
      bf16x8 xh, xl;
      cvt8(xa[ch], xb[ch], xh, xl);
      MFMA16(xh, wfh[0][ch], acc0); MFMA16(xl, wfh[0][ch], acc0); MFMA16(xh, wfl[0][ch], acc0);
      MFMA16(xh, wfh[1][ch], acc1); MFMA16(xl, wfh[1][ch], acc1); MFMA16(xh, wfl[1][ch], acc1);
    }

    // ---- h-part: 16 K=32 chunks, 8-slot pipeline, counted vmcnt ----
    if (t > 0) {
      #pragma unroll
      for (int c = 0; c < 16; ++c) {
        if (c <= 8)       asm volatile("s_waitcnt vmcnt(14)");
        else if (c == 9)  asm volatile("s_waitcnt vmcnt(12)");
        else if (c == 10) asm volatile("s_waitcnt vmcnt(10)");
        else if (c == 11) asm volatile("s_waitcnt vmcnt(8)");
        else if (c == 12) asm volatile("s_waitcnt vmcnt(6)");
        else if (c == 13) asm volatile("s_waitcnt vmcnt(4)");
        else if (c == 14) asm volatile("s_waitcnt vmcnt(2)");
        else              asm volatile("s_waitcnt vmcnt(0)");
        __builtin_amdgcn_sched_barrier(0);
        bf16x8 ah, al;
        unpack(Aa[c & 7], Ab[c & 7], ah, al);
        if (c < 8) {  // refill slot just consumed with chunk c+8
          Aa[c & 7] = ald16(hrow + (c + 8) * 32);
          Ab[c & 7] = ald16(hrow + (c + 8) * 32 + 4);
        }
        int k8 = c * 4 + l4;
        bf16x8 bh0 = ldB(sWhhHi, br0, k8), bl0 = ldB(sWhhLo, br0, k8);
        bf16x8 bh1 = ldB(sWhhHi, br1, k8), bl1 = ldB(sWhhLo, br1, k8);
        MFMA16(ah, bh0, acc0); MFMA16(al, bh0, acc0); MFMA16(ah, bl0, acc0);
        MFMA16(ah, bh1, acc1); MFMA16(al, bh1, acc1); MFMA16(ah, bl1, acc1);
      }
    }

    // ---- gate preactivations to LDS (padded stride 65) ----
    {
      int gr = 16 * rt + 4 * l4;
      int gc = 32 * cp + l15;
      #pragma unroll
      for (int q = 0; q < 4; ++q) {
        sGates[(gr + q) * 65 + gc]      = acc0[q];
        sGates[(gr + q) * 65 + gc + 16] = acc1[q];
      }
    }
    __syncthreads();

    // ---- x(t+1) prefetch (drains at end-of-iteration vmcnt(0)) ----
    {
      int tp = (t + 1 < T_) ? t + 1 : 0;
      const float* xr2 = xrow0 + (size_t)tp * F_;
      #pragma unroll
      for (int ch = 0; ch < 4; ++ch) {
        xa[ch] = pld16(xr2 + ch * 32);
        xb[ch] = pld16(xr2 + ch * 32 + 4);
      }
    }

    // ---- elementwise LSTM update (c in LDS), packed system h store ----
    #pragma unroll
    for (int i = 0; i < 2; ++i) {
      int it = tid + i * 512;
      int rr = it >> 4, uu = it & 15;
      float gi = sGates[rr * 65 + uu]      + sBias[uu];
      float gf = sGates[rr * 65 + 16 + uu] + sBias[16 + uu];
      float gg = sGates[rr * 65 + 32 + uu] + sBias[32 + uu];
      float go = sGates[rr * 65 + 48 + uu] + sBias[48 + uu];
      float ii = 1.f / (1.f + __expf(-gi));
      float ff = 1.f / (1.f + __expf(-gf));
      float gG = 1.f - 2.f / (__expf(2.f * gg) + 1.f);
      float oo = 1.f / (1.f + __expf(-go));
      float c = ff * sC[rr * 16 + uu] + ii * gG;
      sC[rr * 16 + uu] = c;
      float h = oo * (1.f - 2.f / (__expf(2.f * c) + 1.f));
      u16 hb = f2bf(h);
      u16 lb = f2bf(h - bf2f(hb));
      u32 pk = (u32)hb | ((u32)lb << 16);
      size_t idx = (size_t)(64 * m + rr) * H_ + 16 * nb + uu;
      __hip_atomic_store(&hnxt[idx], pk, __ATOMIC_RELAXED, __HIP_MEMORY_SCOPE_SYSTEM);
      if (t == T_ - 1) hT[idx] = h;
    }

    // ---- signal: drain stores (and x prefetch), barrier, one flag store per wg ----
    asm volatile("s_waitcnt vmcnt(0)" ::: "memory");
    __syncthreads();
    if (tid == 0)
      __hip_atomic_store(&fl[m * 32 + nb], (u32)(t + 1), __ATOMIC_RELAXED, __HIP_MEMORY_SCOPE_SYSTEM);
  }
}

// ---------------- head: z = relu(hT @ W1^T + b1) ----------------
__global__ __launch_bounds__(256) void head1(const float* __restrict__ hT,
                                             const float* __restrict__ W1,
                                             const float* __restrict__ b1,
                                             float* __restrict__ z) {
  __shared__ float sA[64][16];
  __shared__ float sBt[16][64];
  int tx = threadIdx.x & 15, ty = threadIdx.x >> 4;
  int row0 = blockIdx.y * 64, col0 = blockIdx.x * 64;
  float acc[4][4] = {};
  for (int k0 = 0; k0 < H_; k0 += 16) {
    int c = threadIdx.x >> 2, kk4 = (threadIdx.x & 3) * 4;
    float4 av = *(const float4*)(hT + (size_t)(row0 + c) * H_ + k0 + kk4);
    *(float4*)&sA[c][kk4] = av;
    float4 bv = *(const float4*)(W1 + (size_t)(col0 + c) * H_ + k0 + kk4);
    sBt[kk4 + 0][c] = bv.x; sBt[kk4 + 1][c] = bv.y;
    sBt[kk4 + 2][c] = bv.z; sBt[kk4 + 3][c] = bv.w;
    __syncthreads();
    #pragma unroll
    for (int kk = 0; kk < 16; ++kk) {
      float a0 = sA[ty * 4 + 0][kk], a1 = sA[ty * 4 + 1][kk];
      float a2 = sA[ty * 4 + 2][kk], a3 = sA[ty * 4 + 3][kk];
      float b0 = sBt[kk][tx * 4 + 0], b1v = sBt[kk][tx * 4 + 1];
      float b2v = sBt[kk][tx * 4 + 2], b3 = sBt[kk][tx * 4 + 3];
      acc[0][0] += a0 * b0; acc[0][1] += a0 * b1v; acc[0][2] += a0 * b2v; acc[0][3] += a0 * b3;
      acc[1][0] += a1 * b0; acc[1][1] += a1 * b1v; acc[1][2] += a1 * b2v; acc[1][3] += a1 * b3;
      acc[2][0] += a2 * b0; acc[2][1] += a2 * b1v; acc[2][2] += a2 * b2v; acc[2][3] += a2 * b3;
      acc[3][0] += a3 * b0; acc[3][1] += a3 * b1v; acc[3][2] += a3 * b2v; acc[3][3] += a3 * b3;
    }
    __syncthreads();
  }
  #pragma unroll
  for (int i = 0; i < 4; ++i)
    #pragma unroll
    for (int j = 0; j < 4; ++j) {
      int rr = row0 + ty * 4 + i, cc = col0 + tx * 4 + j;
      float v = acc[i][j] + b1[cc];
      z[(size_t)rr * LH_ + cc] = v > 0.f ? v : 0.f;
    }
}

// ---------------- head: out[b] = z[b,:] . W2 + b2 ----------------
__global__ __launch_bounds__(256) void head2(const float* __restrict__ z,
                                             const float* __restrict__ W2,
                                             const float* __restrict__ b2,
                                             float* __restrict__ out) {
  int b = blockIdx.x;
  float p = 0.f;
  for (int j = threadIdx.x; j < LH_; j += 256) p += z[(size_t)b * LH_ + j] * W2[j];
  #pragma unroll
  for (int off = 32; off > 0; off >>= 1) p += __shfl_down(p, off);
  __shared__ float red[4];
  if ((threadIdx.x & 63) == 0) red[threadIdx.x >> 6] = p;
  __syncthreads();
  if (threadIdx.x == 0) out[b] = red[0] + red[1] + red[2] + red[3] + b2[0];
}

// ---------------- launch ----------------
extern "C" void kernel_launch(void* const* d_in, const int* in_sizes, int n_in,
                              void* d_out, int out_size, void* d_ws, size_t ws_size,
                              hipStream_t stream) {
  const float* x    = (const float*)d_in[0];
  const float* Wih  = (const float*)d_in[1];
  const float* Whh  = (const float*)d_in[2];
  const float* bih  = (const float*)d_in[3];
  const float* bhh  = (const float*)d_in[4];
  const float* W1   = (const float*)d_in[5];
  const float* b1   = (const float*)d_in[6];
  const float* W2   = (const float*)d_in[7];
  const float* b2   = (const float*)d_in[8];

  char* ws = (char*)d_ws;
  u32* hPk      = (u32*)(ws + O_HPK);
  u32* fl       = (u32*)(ws + O_FL);
  u16* whhHi    = (u16*)(ws + O_WHH_HI);
  u16* whhLo    = (u16*)(ws + O_WHH_LO);
  u16* wihHi    = (u16*)(ws + O_WIH_HI);
  u16* wihLo    = (u16*)(ws + O_WIH_LO);
  float* bias   = (float*)(ws + O_BIAS);
  float* hT     = (float*)(ws + O_HT);
  float* zbuf   = (float*)(ws + O_Z);

  (void)hipMemsetAsync(ws, 0, O_MSET, stream);

  prep_weights<<<G_, 128, 0, stream>>>(Wih, Whh, bih, bhh, whhHi, whhLo, wihHi, wihLo, bias);

  (void)hipFuncSetAttribute((const void*)lstm_persistent,
                            hipFuncAttributeMaxDynamicSharedMemorySize, SMEM_BYTES);

  lstm_persistent<<<256, 512, SMEM_BYTES, stream>>>(x, whhHi, whhLo, wihHi, wihLo,
                                                    bias, hPk, fl, hT);

  head1<<<dim3(LH_ / 64, B_ / 64), 256, 0, stream>>>(hT, W1, b1, zbuf);
  head2<<<B_, 256, 0, stream>>>(zbuf, W2, b2, (float*)d_out);
}